// Round 8
// baseline (98.312 us; speedup 1.0000x reference)
//
#include <hip/hip_runtime.h>
#include <hip/hip_bf16.h>

// Problem constants (fixed shapes from setup_inputs)
constexpr int NPTS = 16384;   // points per batch
constexpr int NCTR = 2048;    // centers per batch
constexpr int NCH  = 64;      // feature channels
constexpr int KK   = 32;      // neighbors per center
constexpr int NB   = 2;       // batches
// radius^2: reference compares d2 < fp32(0.04) (python double 0.2*0.2 -> f32)
#define R2 0.04f

// -------- Kernel A (prep): transpose feats + pack points --------
// blocks [0,512):   transpose features (b,64,16384) -> (b,16384,64) into ws
// blocks [512,544): pack points -> float4 (2x,2y,2z,p2) into ws
// Coords stored DOUBLED: d2 = (c2+p2) - ((2x)cx+(2y)cy+(2z)cz) is bit-equal
// to (c2+p2) - 2*cp because fp rounding commutes with *2^k. p2 uses the
// exact R1-verified formula (contract off) -> selection bit-identical.
__global__ __launch_bounds__(256) void prep_kernel(
    const float* __restrict__ points,   // (2,16384,3)
    const float* __restrict__ feats,    // (2,64,16384)
    float* __restrict__ featsT,         // ws: (2,16384,64)
    float4* __restrict__ packed)        // ws: (2*16384) {2x,2y,2z,p2}
{
#pragma clang fp contract(off)
    __shared__ float tile[64][65];      // +1 pad: conflict-free transpose

    if (blockIdx.x < 512) {
        const int b  = blockIdx.x >> 8;
        const int n0 = (blockIdx.x & 255) * 64;
        const int t  = threadIdx.x;
        const int nl = t & 63;
        const int q  = t >> 6;

        const float* fb = feats + (size_t)b * NCH * NPTS;
#pragma unroll
        for (int r = 0; r < 16; ++r) {
            int c = r * 4 + q;
            tile[c][nl] = fb[(size_t)c * NPTS + n0 + nl];
        }
        __syncthreads();
        float* ftb = featsT + ((size_t)b * NPTS + n0) * NCH;
#pragma unroll
        for (int r = 0; r < 16; ++r) {
            int n = r * 4 + q;
            ftb[(size_t)n * NCH + nl] = tile[nl][n];   // 2-way max (free)
        }
        return;
    }

    // ---------------- pack: 32 blocks x 256 thr x 4 pts ----------------
    const int tid = (blockIdx.x - 512) * 256 + threadIdx.x;  // 0..8191
#pragma unroll
    for (int s = 0; s < 4; ++s) {
        const int i = tid + s * 8192;                        // 0..32767 (b*NPTS+n)
        const float x = points[3 * i + 0];
        const float y = points[3 * i + 1];
        const float z = points[3 * i + 2];
        const float p2 = (x * x + y * y) + z * z;            // exact R1 formula
        packed[i] = make_float4(x + x, y + y, z + z, p2);    // doubled (exact)
    }
}

// -------- Kernel B: query+group, one block/center, QUARTERED SCAN --------
// R2-R7 invariant: query ~30us because tail centers (H~70 hits -> 32nd hit
// near index 16384*32/H) scan 15-32 chunks x ~1 memory-latency each, alone
// on their SIMD. Here wave w scans ONLY [4096w,4096w+4096) = max 8 chunks
// (serial depth /4), no inter-wave sync during scan (R5's per-iter barriers
// were the poison). Quarters are index-ordered, so global first-32 = first
// 32 of concat(capped quarter lists) -- exact. ~9.4 KB LDS.
__global__ __launch_bounds__(256, 4) void query_group(
    const float4* __restrict__ packed,  // (2,16384) {2x,2y,2z,p2}
    const float* __restrict__ centers,  // (2,2048,3)
    const float* __restrict__ featsT,   // (2,16384,64)
    float* __restrict__ out_xyz,        // (2,3,2048,32)
    float* __restrict__ out_feat)       // (2,64,2048,32)
{
#pragma clang fp contract(off)          // keep numpy-exact d2 (absmax=0 since R1)
    __shared__ int   lidx[4][KK];       // per-wave first-32 within its quarter
    __shared__ int   lcnt[4];           // per-wave count, capped at KK
    __shared__ int   idxs[KK];          // merged global first-32
    __shared__ float sf[KK][68];        // gather staging; rows 16B-aligned

    const int wave = threadIdx.x >> 6;
    const int lane = threadIdx.x & 63;
    const int cg   = blockIdx.x;        // 0..4095
    const int b    = cg >> 11;
    const int g    = cg & (NCTR - 1);

    const float4* pk = packed + (size_t)b * NPTS;
    const float* cc = centers + (size_t)cg * 3;
    const float cx = cc[0], cy = cc[1], cz = cc[2];
    const float c2 = (cx * cx + cy * cy) + cz * cz;

    // ---- wave-private scan of quarter [4096w, 4096w+4096), 8 chunks ----
    const int qb = wave * 4096 + lane;
    float4 cur[8], nxt[8];
#pragma unroll
    for (int j = 0; j < 8; ++j) cur[j] = pk[qb + j * 64];
    int cnt = 0;
    const unsigned long long lmask = (1ull << lane) - 1ull;
    int* lp = lidx[wave];
    for (int c = 0; c < 8; ++c) {
        const int nc = (c < 7) ? c + 1 : 0;      // wrap prefetch (discarded)
#pragma unroll
        for (int j = 0; j < 8; ++j) nxt[j] = pk[qb + nc * 512 + j * 64];

        // phase 1: 8 independent ballots
        unsigned long long m[8];
#pragma unroll
        for (int j = 0; j < 8; ++j) {
            const float4 v = cur[j];
            const float cp2 = (cx * v.x + cy * v.y) + cz * v.z;  // == 2*cp exact
            m[j] = __ballot((c2 + v.w) - cp2 < R2);
        }
        // phase 2: ordered merge into wave-local list
        int run = cnt;
        const int base = wave * 4096 + c * 512;
#pragma unroll
        for (int j = 0; j < 8; ++j) {
            if ((m[j] >> lane) & 1ull) {
                const int slot = run + __popcll(m[j] & lmask);
                if (slot < KK) lp[slot] = base + j * 64 + lane;
            }
            run += (int)__popcll(m[j]);
        }
        cnt = run;
        if (cnt >= KK) break;                    // wave-uniform
#pragma unroll
        for (int j = 0; j < 8; ++j) cur[j] = nxt[j];
    }
    if (lane == 0) lcnt[wave] = cnt < KK ? cnt : KK;
    __syncthreads();                             // the ONLY scan barrier

    // ---- merge (ordered concat of capped lists) + pad + grouped_xyz ----
    const int t = threadIdx.x;
    const int n0 = lcnt[0], n01 = n0 + lcnt[1], n012 = n01 + lcnt[2];
    const int total = n012 + lcnt[3];
    const int cpd = total < KK ? total : KK;
    if (t < KK) {
        int first;
        if (n0 > 0)        first = lidx[0][0];
        else if (n01 > 0)  first = lidx[1][0];
        else if (n012 > 0) first = lidx[2][0];
        else if (total > 0) first = lidx[3][0];
        else               first = 0;
        int id;
        if (t < cpd) {
            int w, off;
            if (t < n0)        { w = 0; off = t; }
            else if (t < n01)  { w = 1; off = t - n0; }
            else if (t < n012) { w = 2; off = t - n01; }
            else               { w = 3; off = t - n012; }
            id = lidx[w][off];
        } else {
            id = first;
        }
        idxs[t] = id;
        const float4 v = pk[id];
        const float px = 0.5f * v.x, py = 0.5f * v.y, pz = 0.5f * v.z;  // exact
        const size_t ob = (((size_t)b * 3 + 0) * NCTR + g) * KK + t;
        out_xyz[ob + (size_t)0 * NCTR * KK] = (px - cx) / 0.2f;
        out_xyz[ob + (size_t)1 * NCTR * KK] = (py - cy) / 0.2f;
        out_xyz[ob + (size_t)2 * NCTR * KK] = (pz - cz) / 0.2f;
    }
    __syncthreads();

    // ---- gather: wave w loads rows 8w..8w+7 (2 b128 instrs/wave) ----
    const int li = lane & 15, r = lane >> 4;
    const float* ftb = featsT + (size_t)b * NPTS * NCH;
#pragma unroll
    for (int i = 0; i < 2; ++i) {
        const int k = wave * 8 + i * 4 + r;
        const float4 v = *((const float4*)(ftb + (size_t)idxs[k] * NCH) + li);
        *(float4*)&sf[k][4 * li] = v;
    }
    __syncthreads();

    // ---- write: thread owns k-quad [4kq,4kq+4) of channel c; 2 passes ----
    const int kq = t & 7;
    const int c0 = t >> 3;              // 0..31
    const size_t ob = ((size_t)b * NCH * NCTR + g) * KK;
#pragma unroll
    for (int p = 0; p < 2; ++p) {
        const int c = c0 + 32 * p;
        float4 w;
        w.x = sf[4 * kq + 0][c];        // 4-way LDS conflict: short epilogue
        w.y = sf[4 * kq + 1][c];
        w.z = sf[4 * kq + 2][c];
        w.w = sf[4 * kq + 3][c];
        *(float4*)(out_feat + ob + (size_t)c * NCTR * KK + 4 * kq) = w;
    }
}

// -------- Fallback: R2 fused kernel (used only if ws is too small) --------
__global__ __launch_bounds__(256) void ballquery_group(
    const float* __restrict__ points, const float* __restrict__ centers,
    const float* __restrict__ feats, float* __restrict__ out_xyz,
    float* __restrict__ out_feat)
{
#pragma clang fp contract(off)
    __shared__ int   s_idx[4][KK];
    __shared__ float s_f[4][KK][65];
    const int wave = threadIdx.x >> 6, lane = threadIdx.x & 63;
    const int cg = blockIdx.x * 4 + wave;
    const int b = cg >> 11, g = cg & (NCTR - 1);
    const float* pb = points + (size_t)b * NPTS * 3;
    const float* cc = centers + (size_t)cg * 3;
    const float cx = cc[0], cy = cc[1], cz = cc[2];
    const float c2 = (cx * cx + cy * cy) + cz * cz;
    int* idxs = s_idx[wave];
    int cnt = 0;
    for (int base = 0; base < NPTS; base += 64) {
        const int i = base + lane;
        const float px = pb[i * 3 + 0], py = pb[i * 3 + 1], pz = pb[i * 3 + 2];
        const float p2 = (px * px + py * py) + pz * pz;
        const float cp = (cx * px + cy * py) + cz * pz;
        const float d2 = (c2 + p2) - 2.0f * cp;
        const bool hit = d2 < R2;
        const unsigned long long m = __ballot(hit);
        if (hit) {
            const int slot = cnt + __popcll(m & ((1ull << lane) - 1ull));
            if (slot < KK) idxs[slot] = i;
        }
        cnt += (int)__popcll(m);
        if (cnt >= KK) break;
    }
    __syncthreads();
    const int cpd = cnt < KK ? cnt : KK;
    const int first = (cnt > 0) ? idxs[0] : 0;
    if (lane < KK) idxs[lane] = (lane < cpd) ? idxs[lane] : first;
    __syncthreads();
    if (lane < KK) {
        const int id = idxs[lane];
        const float px = pb[id * 3 + 0], py = pb[id * 3 + 1], pz = pb[id * 3 + 2];
        const size_t ob = (((size_t)b * 3 + 0) * NCTR + g) * KK + lane;
        out_xyz[ob + (size_t)0 * NCTR * KK] = (px - cx) / 0.2f;
        out_xyz[ob + (size_t)1 * NCTR * KK] = (py - cy) / 0.2f;
        out_xyz[ob + (size_t)2 * NCTR * KK] = (pz - cz) / 0.2f;
    }
    float (*sf)[65] = s_f[wave];
    const float* fb = feats + (size_t)b * NCH * NPTS;
    for (int k = 0; k < KK; ++k) {
        const int id = idxs[k];
        sf[k][lane] = fb[(size_t)lane * NPTS + id];
    }
    __syncthreads();
    const int k = lane & 31, ch = lane >> 5;
    const size_t ob = ((size_t)b * NCH * NCTR + g) * KK;
#pragma unroll
    for (int cc2 = 0; cc2 < 32; ++cc2) {
        const int c = cc2 * 2 + ch;
        out_feat[ob + (size_t)c * NCTR * KK + k] = sf[k][c];
    }
}

extern "C" void kernel_launch(void* const* d_in, const int* in_sizes, int n_in,
                              void* d_out, int out_size, void* d_ws, size_t ws_size,
                              hipStream_t stream) {
    const float* points  = (const float*)d_in[0];   // (2,16384,3)
    const float* centers = (const float*)d_in[1];   // (2,2048,3)
    const float* feats   = (const float*)d_in[2];   // (2,64,16384)

    float* out      = (float*)d_out;
    float* out_xyz  = out;                                    // (2,3,2048,32)
    float* out_feat = out + (size_t)NB * 3 * NCTR * KK;       // (2,64,2048,32)

    const size_t ftBytes = (size_t)NB * NPTS * NCH * sizeof(float);   // 8 MB
    const size_t pkBytes = (size_t)NB * NPTS * 4 * sizeof(float);     // 512 KB

    if (ws_size >= ftBytes + pkBytes) {
        float*  featsT = (float*)d_ws;
        float4* packed = (float4*)((char*)d_ws + ftBytes);
        // blocks [0,512): transpose; [512,544): pack points
        prep_kernel<<<544, 256, 0, stream>>>(points, feats, featsT, packed);
        // one block per center; 4 waves quarter the index range
        query_group<<<NB * NCTR, 256, 0, stream>>>(
            packed, centers, featsT, out_xyz, out_feat);
    } else {
        ballquery_group<<<(NB * NCTR) / 4, 256, 0, stream>>>(
            points, centers, feats, out_xyz, out_feat);
    }
}